// Round 1
// baseline (612.331 us; speedup 1.0000x reference)
//
#include <hip/hip_runtime.h>

constexpr int DIM = 96;
constexpr int HW  = DIM * DIM;            // 9216
constexpr int DHW = DIM * DIM * DIM;      // 884736
constexpr int NC  = 64;

constexpr int TZ = 4, TY = 8, TX = 32;    // spatial tile per block (4 outs/thread in x)
constexpr int LZ = TZ;                    // dz fixed per block -> only TZ z-planes staged
constexpr int LY = TY + 2;                // 10 (y halo)
constexpr int LXP = 36;                   // 34 live x + 2 pad -> 144B rows (16B aligned)
constexpr int LDS_N   = LZ * LY * LXP;    // 1440 words actually read
constexpr int LDS_PAD = 1536;             // 6*256 -> branch-free staging (pad = dummy loads)
constexpr int NSTG = LDS_PAD / 256;       // 6 dword loads / thread / channel

typedef const __attribute__((address_space(1))) unsigned int* gas_ptr;
typedef __attribute__((address_space(3))) unsigned int* las_ptr;

__global__ __launch_bounds__(256, 6)     // cap ~85 VGPR -> 6 waves/SIMD (24/CU)
void wincorr_kernel(const float* __restrict__ fixed_,
                    const float* __restrict__ moving,
                    float* __restrict__ out)
{
    __shared__ __align__(16) float sm[2][LDS_PAD];   // 12 KB double buffer

    const int tid = threadIdx.x;
    const int tx = tid & 7;          // 8 x-chunks of 4
    const int ty = (tid >> 3) & 7;   // 8 y
    const int tz = tid >> 6;         // 4 z (wave id)

    // blockIdx.x packs (x-tile, dz); dz fastest so sibling taps are dispatch-adjacent
    const int bxp = blockIdx.x;
    const int xt  = bxp / 3;
    const int dz  = bxp - xt * 3;
    const int bx0 = xt * TX;
    const int by0 = blockIdx.y * TY;
    const int bz0 = blockIdx.z * TZ;

    // Channel-invariant staging source offsets (edge clamp here).
    // Staged plane lz <-> gz = clamp(bz0 + dz - 1 + lz): thread tz reads plane lz = tz.
    int g_off[NSTG];
#pragma unroll
    for (int i = 0; i < NSTG; ++i) {
        const int t  = tid + i * 256;
        const int lz = t / (LY * LXP);
        const int r  = t - lz * (LY * LXP);
        const int ly = r / LXP;
        const int lx = r - ly * LXP;            // lx 34,35 = pad -> dummy (clamped, never read)
        const int gz = min(max(bz0 + dz - 1 + lz, 0), DIM - 1);
        const int gy = min(max(by0 - 1 + ly, 0), DIM - 1);
        const int gx = min(max(bx0 - 1 + lx, 0), DIM - 1);
        g_off[i] = gz * HW + gy * DIM + gx;
    }

    const int z = bz0 + tz, y = by0 + ty, x0 = bx0 + 4 * tx;
    const int foff = z * HW + y * DIM + x0;

    float acc[9][4];
#pragma unroll
    for (int k = 0; k < 9; ++k)
#pragma unroll
        for (int j = 0; j < 4; ++j) acc[k][j] = 0.f;

    // Prologue: async-stage channel 0 into buffer 0, prefetch fixed ch0
#pragma unroll
    for (int i = 0; i < NSTG; ++i)
        __builtin_amdgcn_global_load_lds((gas_ptr)(moving + g_off[i]),
                                         (las_ptr)&sm[0][tid + i * 256], 4, 0, 0);
    float4 pf = *(const float4*)(fixed_ + foff);
    __syncthreads();                             // vmcnt(0) drain -> buf0 ready

    const int rbase = (tz * LY + ty) * LXP + 4 * tx;

    for (int c = 0; c < NC; ++c) {
        const int cur = c & 1;

        // Issue next channel's staging first: HW DMA overlaps the compute below,
        // drained by the single barrier at loop end.
        if (c + 1 < NC) {
            const float* mc = moving + (size_t)(c + 1) * DHW;
            float* dst = sm[cur ^ 1];
#pragma unroll
            for (int i = 0; i < NSTG; ++i)
                __builtin_amdgcn_global_load_lds((gas_ptr)(mc + g_off[i]),
                                                 (las_ptr)&dst[tid + i * 256], 4, 0, 0);
        }
        const float4 fv = pf;
        if (c + 1 < NC)
            pf = *(const float4*)(fixed_ + (size_t)(c + 1) * DHW + foff);

        const float* buf = sm[cur];
#pragma unroll
        for (int dy = 0; dy < 3; ++dy) {
            const float* row = buf + rbase + dy * LXP;   // 16B aligned, bank-balanced
            const float4 w0 = *(const float4*)row;
            const float2 w1 = *(const float2*)(row + 4);
            const float w[6] = {w0.x, w0.y, w0.z, w0.w, w1.x, w1.y};
            const int kb = dy * 3;
#pragma unroll
            for (int dx = 0; dx < 3; ++dx) {
                acc[kb + dx][0] += fv.x * w[dx + 0];
                acc[kb + dx][1] += fv.y * w[dx + 1];
                acc[kb + dx][2] += fv.z * w[dx + 2];
                acc[kb + dx][3] += fv.w * w[dx + 3];
            }
        }
        __syncthreads();   // one barrier/channel: reads of buf done, next buf landed
    }

    // Epilogue: this block owns taps dz*9 .. dz*9+8; scale 64^-0.5 = 0.125
#pragma unroll
    for (int k = 0; k < 9; ++k) {
        float4 o;
        o.x = acc[k][0] * 0.125f;
        o.y = acc[k][1] * 0.125f;
        o.z = acc[k][2] * 0.125f;
        o.w = acc[k][3] * 0.125f;
        *(float4*)(out + (size_t)(dz * 9 + k) * DHW + foff) = o;
    }
}

extern "C" void kernel_launch(void* const* d_in, const int* in_sizes, int n_in,
                              void* d_out, int out_size, void* d_ws, size_t ws_size,
                              hipStream_t stream) {
    const float* fixed_  = (const float*)d_in[0];
    const float* moving  = (const float*)d_in[1];
    float* out = (float*)d_out;
    dim3 grid(3 * (DIM / TX), DIM / TY, DIM / TZ);   // 9 x 12 x 24 = 2592 blocks
    dim3 block(256);
    wincorr_kernel<<<grid, block, 0, stream>>>(fixed_, moving, out);
}